// Round 1
// baseline (369.782 us; speedup 1.0000x reference)
//
#include <hip/hip_runtime.h>
#include <hip/hip_bf16.h>
#include <math.h>

typedef unsigned short u16;
typedef unsigned int   u32;
typedef __bf16 bf16x8 __attribute__((ext_vector_type(8)));
typedef float  f32x4  __attribute__((ext_vector_type(4)));

#define NRAYS 262144
#define NBLK  (NRAYS / 64)

// Packed-weight layer offsets (in u16 elements) = chunk_start * 512
enum : size_t { PO0=0, PO1=16384, PO2=81920, PO3=147456, PO4=212992,
                PO5=294912, PO6=360448, PO7=425984, PO8=491520, PO9=528384 };
#define TOTAL_PACK_ELEMS 530432   // = 1036 chunks * 512

__device__ __forceinline__ u16 f2bf(float x) {
  u32 u = __float_as_uint(x);
  u32 r = (u + 0x7FFFu + ((u >> 16) & 1u)) >> 16;   // RTN-even
  return (u16)r;
}

// ---------------------------------------------------------------------------
// Weight pack kernel: fp32 W[K][N] -> bf16 chunks in MFMA A-fragment order.
// chunk = kstep*MT + mtile; within chunk: [lane][j] holds
//   A[m = mtile*16 + (lane&15)][k = kstep*32 + (lane>>4)*8 + j] = W[k][m]
// ---------------------------------------------------------------------------
struct PackArgs {
  const float* src[10];
  int K[10];       // real K (rows of W)
  int N[10];       // real N (cols of W = out channels)
  int l2mt[10];    // log2(mtiles per kstep)
  int cstart[11];  // chunk prefix sums
};

__global__ __launch_bounds__(256) void pack_w(PackArgs a, u16* __restrict__ dst)
{
  int e = blockIdx.x * 256 + threadIdx.x;
  if (e >= TOTAL_PACK_ELEMS) return;
  int chunk = e >> 9;
  int li = 0;
  #pragma unroll
  for (int t = 1; t < 10; ++t) li += (chunk >= a.cstart[t]) ? 1 : 0;
  int lc = chunk - a.cstart[li];
  int ks = lc >> a.l2mt[li];
  int mt = lc - (ks << a.l2mt[li]);
  int lane = (e >> 3) & 63, j = e & 7;
  int k = ks * 32 + ((lane >> 4) << 3) + j;
  int n = mt * 16 + (lane & 15);
  float v = 0.f;
  if (k < a.K[li] && n < a.N[li]) v = a.src[li][(size_t)k * a.N[li] + n];
  dst[e] = f2bf(v);
}

// ---------------------------------------------------------------------------
// Fused NeRF kernel: 64 rays/block, 4 waves, activations in LDS [ray][ch].
// A = packed weights (global, L2-hot), B = activations (LDS, ds_read_b128),
// D(row=out_ch, col=ray) -> epilogue ds_write_b64 of 4 consecutive channels.
// ---------------------------------------------------------------------------
template<int M>
__device__ __forceinline__ void zacc(f32x4 a[M][4]) {
  #pragma unroll
  for (int i = 0; i < M; ++i)
    #pragma unroll
    for (int j = 0; j < 4; ++j) a[i][j] = (f32x4){0.f, 0.f, 0.f, 0.f};
}

template<int MT_W, int NSTEPS>
__device__ __forceinline__ void gseg(f32x4 acc[MT_W][4],
    const u16* __restrict__ act, int astride,
    const u16* __restrict__ wl, int mt_total, int mt0, int ksbase, int lane)
{
  const int lhi = (lane >> 4) << 3, llo = lane & 15;
  #pragma unroll
  for (int ks = 0; ks < NSTEPS; ++ks) {
    const u16* ap = act + (size_t)llo * astride + ks * 32 + lhi;
    bf16x8 b[4];
    #pragma unroll
    for (int nt = 0; nt < 4; ++nt)
      b[nt] = *(const bf16x8*)(ap + (size_t)nt * 16 * astride);
    const u16* wp = wl + ((size_t)(ksbase + ks) * mt_total + mt0) * 512 + lane * 8;
    bf16x8 a[MT_W];
    #pragma unroll
    for (int mt = 0; mt < MT_W; ++mt)
      a[mt] = *(const bf16x8*)(wp + (size_t)mt * 512);
    #pragma unroll
    for (int mt = 0; mt < MT_W; ++mt)
      #pragma unroll
      for (int nt = 0; nt < 4; ++nt)
        acc[mt][nt] = __builtin_amdgcn_mfma_f32_16x16x32_bf16(a[mt], b[nt], acc[mt][nt], 0, 0, 0);
  }
}

template<int MT_W, bool RELU>
__device__ __forceinline__ void zstore(f32x4 acc[MT_W][4],
    const float* __restrict__ bias, int ch0, u16* dst, int dstride, int lane)
{
  const int llo = lane & 15, cq = (lane >> 4) << 2;
  #pragma unroll
  for (int mt = 0; mt < MT_W; ++mt) {
    int ch = ch0 + mt * 16 + cq;
    float4 bv = *(const float4*)(bias + ch);
    #pragma unroll
    for (int nt = 0; nt < 4; ++nt) {
      f32x4 v = acc[mt][nt];
      float x0 = v.x + bv.x, x1 = v.y + bv.y, x2 = v.z + bv.z, x3 = v.w + bv.w;
      if (RELU) { x0 = fmaxf(x0, 0.f); x1 = fmaxf(x1, 0.f);
                  x2 = fmaxf(x2, 0.f); x3 = fmaxf(x3, 0.f); }
      uint2 pk;
      pk.x = (u32)f2bf(x0) | ((u32)f2bf(x1) << 16);
      pk.y = (u32)f2bf(x2) | ((u32)f2bf(x3) << 16);
      *(uint2*)(dst + (size_t)(nt * 16 + llo) * dstride + ch) = pk;
    }
  }
}

__global__ __launch_bounds__(256, 3) void nerf_fused(
    const float* __restrict__ pos,  const float* __restrict__ dirv,
    const float* __restrict__ b00,  const float* __restrict__ b01,
    const float* __restrict__ b02,  const float* __restrict__ b03,
    const float* __restrict__ b10,  const float* __restrict__ b11,
    const float* __restrict__ b12,  const float* __restrict__ b13,
    const float* __restrict__ cb0,  const float* __restrict__ cb1,
    const u16* __restrict__ W, float* __restrict__ out)
{
  // strides chosen so byte-stride/4 mod 32 gives only free 2-way bank aliasing
  __shared__ __align__(16) u16 zb[64 * 264];    // activations [ray][ch<=256]
  __shared__ __align__(16) u16 peb[64 * 72];    // pos encoding, 63 (+pad) cols
  __shared__ __align__(16) u16 deb[64 * 40];    // dir encoding, 27 (+pad) cols
  __shared__ float xyz[64 * 6];

  const int tid = threadIdx.x;
  const int rb  = blockIdx.x * 64;
  const int lane = tid & 63, wid = tid >> 6;

  if (tid < 192) {
    int r = tid / 3, c = tid - r * 3;
    xyz[r * 6 + c]     = pos[(size_t)(rb + r) * 3 + c];
    xyz[r * 6 + 3 + c] = dirv[(size_t)(rb + r) * 3 + c];
  }
  __syncthreads();

  // pe[r]: cols 0..2 = x, 3+t = sin(x_j*2^l), 33+t = cos, t=j*10+l, col63 = 0
  for (int i = tid; i < 64 * 30; i += 256) {
    int r = i / 30, t = i - r * 30;
    int j = t / 10, l = t - j * 10;
    float x = xyz[r * 6 + j] * (float)(1 << l);
    float s, c; sincosf(x, &s, &c);
    peb[r * 72 + 3 + t]  = f2bf(s);
    peb[r * 72 + 33 + t] = f2bf(c);
  }
  for (int i = tid; i < 64 * 4; i += 256) {
    int r = i >> 2, c = i & 3;
    peb[r * 72 + (c < 3 ? c : 63)] = (c < 3) ? f2bf(xyz[r * 6 + c]) : (u16)0;
  }
  // de[r]: cols 0..2 = d, 3+t = sin, 15+t = cos, t=j*4+l, cols 27..31 = 0
  for (int i = tid; i < 64 * 12; i += 256) {
    int r = i / 12, t = i - r * 12;
    int j = t >> 2, l = t & 3;
    float x = xyz[r * 6 + 3 + j] * (float)(1 << l);
    float s, c; sincosf(x, &s, &c);
    deb[r * 40 + 3 + t]  = f2bf(s);
    deb[r * 40 + 15 + t] = f2bf(c);
  }
  for (int i = tid; i < 64 * 8; i += 256) {
    int r = i >> 3, c = i & 7;
    deb[r * 40 + (c < 3 ? c : 24 + c)] = (c < 3) ? f2bf(xyz[r * 6 + 3 + c]) : (u16)0;
  }
  __syncthreads();

  f32x4 acc[4][4];

  // L0: pe(64) -> 256
  zacc<4>(acc);
  gseg<4, 2>(acc, peb, 72, W + PO0, 16, wid * 4, 0, lane);
  __syncthreads();
  zstore<4, true>(acc, b00, wid * 64, zb, 264, lane);
  __syncthreads();
  // L1..L3: 256 -> 256
  zacc<4>(acc);
  gseg<4, 8>(acc, zb, 264, W + PO1, 16, wid * 4, 0, lane);
  __syncthreads();
  zstore<4, true>(acc, b01, wid * 64, zb, 264, lane);
  __syncthreads();
  zacc<4>(acc);
  gseg<4, 8>(acc, zb, 264, W + PO2, 16, wid * 4, 0, lane);
  __syncthreads();
  zstore<4, true>(acc, b02, wid * 64, zb, 264, lane);
  __syncthreads();
  zacc<4>(acc);
  gseg<4, 8>(acc, zb, 264, W + PO3, 16, wid * 4, 0, lane);
  __syncthreads();
  zstore<4, true>(acc, b03, wid * 64, zb, 264, lane);
  __syncthreads();
  // L4: concat(z, pe) 319 -> 256  (k 0..255 = z, 256..318 = pe)
  zacc<4>(acc);
  gseg<4, 8>(acc, zb, 264, W + PO4, 16, wid * 4, 0, lane);
  gseg<4, 2>(acc, peb, 72, W + PO4, 16, wid * 4, 8, lane);
  __syncthreads();
  zstore<4, true>(acc, b10, wid * 64, zb, 264, lane);
  __syncthreads();
  // L5, L6: 256 -> 256 relu
  zacc<4>(acc);
  gseg<4, 8>(acc, zb, 264, W + PO5, 16, wid * 4, 0, lane);
  __syncthreads();
  zstore<4, true>(acc, b11, wid * 64, zb, 264, lane);
  __syncthreads();
  zacc<4>(acc);
  gseg<4, 8>(acc, zb, 264, W + PO6, 16, wid * 4, 0, lane);
  __syncthreads();
  zstore<4, true>(acc, b12, wid * 64, zb, 264, lane);
  __syncthreads();
  // L7: 256 -> 256, NO relu
  zacc<4>(acc);
  gseg<4, 8>(acc, zb, 264, W + PO7, 16, wid * 4, 0, lane);
  __syncthreads();
  zstore<4, false>(acc, b13, wid * 64, zb, 264, lane);
  __syncthreads();
  // L8: concat(z, de) 283 -> 128 relu (k 0..255 = z, 256..282 = de)
  {
    f32x4 acc2[2][4];
    zacc<2>(acc2);
    gseg<2, 8>(acc2, zb, 264, W + PO8, 8, wid * 2, 0, lane);
    gseg<2, 1>(acc2, deb, 40, W + PO8, 8, wid * 2, 8, lane);
    __syncthreads();
    zstore<2, true>(acc2, cb0, wid * 32, zb, 264, lane);
    __syncthreads();
  }
  // L9: 128 -> 4 + epilogue. Each wave handles its 16 rays (one ray-tile).
  {
    const u16* W9 = W + PO9;
    const int lhi = (lane >> 4) << 3, llo = lane & 15;
    f32x4 c9 = (f32x4){0.f, 0.f, 0.f, 0.f};
    #pragma unroll
    for (int ks = 0; ks < 4; ++ks) {
      bf16x8 b = *(const bf16x8*)(zb + (size_t)(wid * 16 + llo) * 264 + ks * 32 + lhi);
      bf16x8 a = *(const bf16x8*)(W9 + (size_t)ks * 512 + lane * 8);
      c9 = __builtin_amdgcn_mfma_f32_16x16x32_bf16(a, b, c9, 0, 0, 0);
    }
    if ((lane >> 4) == 0) {   // rows 0..3 = out channels 0..3
      int ray = rb + wid * 16 + llo;
      float o0 = c9.x + cb1[0];
      float o1 = c9.y + cb1[1];
      float o2 = c9.z + cb1[2];
      float dv = c9.w + cb1[3];
      out[ray] = (dv > 8.f) ? dv : log1pf(expf(dv));
      float* rgb = out + NRAYS + (size_t)ray * 3;
      rgb[0] = 1.f / (1.f + expf(-o0));
      rgb[1] = 1.f / (1.f + expf(-o1));
      rgb[2] = 1.f / (1.f + expf(-o2));
    }
  }
}

// ---------------------------------------------------------------------------
extern "C" void kernel_launch(void* const* d_in, const int* in_sizes, int n_in,
                              void* d_out, int out_size, void* d_ws, size_t ws_size,
                              hipStream_t stream)
{
  (void)in_sizes; (void)n_in; (void)out_size; (void)ws_size;
  const float* pos  = (const float*)d_in[0];
  const float* dirv = (const float*)d_in[1];
  // weights at odd-ish slots: w00=5,w01=7,w02=9,w03=11,w10=13,w11=15,w12=17,w13=19,cw0=21,cw1=23
  PackArgs pa;
  const int widx[10] = {5, 7, 9, 11, 13, 15, 17, 19, 21, 23};
  const int K[10]    = {63, 256, 256, 256, 319, 256, 256, 256, 283, 128};
  const int Nn[10]   = {256, 256, 256, 256, 256, 256, 256, 256, 128, 4};
  const int L2MT[10] = {4, 4, 4, 4, 4, 4, 4, 4, 3, 0};
  const int CS[11]   = {0, 32, 160, 288, 416, 576, 704, 832, 960, 1032, 1036};
  for (int i = 0; i < 10; ++i) {
    pa.src[i] = (const float*)d_in[widx[i]];
    pa.K[i] = K[i]; pa.N[i] = Nn[i]; pa.l2mt[i] = L2MT[i];
  }
  for (int i = 0; i < 11; ++i) pa.cstart[i] = CS[i];

  u16* wp = (u16*)d_ws;
  hipLaunchKernelGGL(pack_w, dim3(TOTAL_PACK_ELEMS / 256), dim3(256), 0, stream, pa, wp);

  hipLaunchKernelGGL(nerf_fused, dim3(NBLK), dim3(256), 0, stream,
      pos, dirv,
      (const float*)d_in[6],  (const float*)d_in[8],
      (const float*)d_in[10], (const float*)d_in[12],
      (const float*)d_in[14], (const float*)d_in[16],
      (const float*)d_in[18], (const float*)d_in[20],
      (const float*)d_in[22], (const float*)d_in[24],
      wp, (float*)d_out);
}